// Round 4
// baseline (12487.723 us; speedup 1.0000x reference)
//
#include <hip/hip_runtime.h>
#include <hip/hip_bf16.h>
#include <stdint.h>

// Problem dims (fixed): B=16 S=1024 D=768 NH=4 hd=192 DFF=3072 NL=2 C=3
#define Bb 16
#define Ss 1024
#define Dd 768
#define HDd 192

typedef __attribute__((ext_vector_type(8))) short short8;   // 8 bf16 (4 VGPRs)
typedef __attribute__((ext_vector_type(4))) float f32x4;

__device__ __forceinline__ short f2bf(float f) {
  union { __hip_bfloat16 h; short s; } u;
  u.h = __float2bfloat16(f);
  return u.s;
}
__device__ __forceinline__ short8 cvt8(float4 lo, float4 hi) {
  short8 r;
  r[0] = f2bf(lo.x); r[1] = f2bf(lo.y); r[2] = f2bf(lo.z); r[3] = f2bf(lo.w);
  r[4] = f2bf(hi.x); r[5] = f2bf(hi.y); r[6] = f2bf(hi.z); r[7] = f2bf(hi.w);
  return r;
}

enum { EPI_F32 = 0, EPI_GELU = 1, EPI_MEANACC = 2 };

// C[m,n] = sum_k A[m,k]*Bw[n,k] (+bias[n], +epilogue). fp32 in/out, bf16 MFMA inside.
// A: [Mchunk,K] row-major fp32 (pointer pre-offset), Bw: [N,K] row-major fp32.
template <int EPI>
__global__ __launch_bounds__(256) void gemm_bt(
    const float* __restrict__ A, const float* __restrict__ Bw,
    const float* __restrict__ bias, void* __restrict__ outp,
    const int N, const int K)
{
  constexpr int TM = 128, TN = 128, BK = 32;
  __shared__ __align__(16) short As[TM * BK];
  __shared__ __align__(16) short Bs[TN * BK];

  const int tid = threadIdx.x;
  const int wave = tid >> 6, lane = tid & 63;
  const int l16 = lane & 15, quad = lane >> 4;
  const int wm = wave >> 1, wn = wave & 1;
  const size_t m0 = (size_t)blockIdx.y * TM;
  const size_t n0 = (size_t)blockIdx.x * TN;

  // staging: 512 chunks of 8 elements per tile; thread handles chunks tid and 256+tid
  const int c0 = tid, c1 = 256 + tid;
  const float* Ag0 = A + (m0 + (c0 >> 2)) * K + (c0 & 3) * 8;
  const float* Ag1 = A + (m0 + (c1 >> 2)) * K + (c1 & 3) * 8;
  const float* Bg0 = Bw + (n0 + (c0 >> 2)) * K + (c0 & 3) * 8;
  const float* Bg1 = Bw + (n0 + (c1 >> 2)) * K + (c1 & 3) * 8;

  f32x4 acc[4][4];
#pragma unroll
  for (int i = 0; i < 4; ++i)
#pragma unroll
    for (int j = 0; j < 4; ++j) acc[i][j] = (f32x4){0.f, 0.f, 0.f, 0.f};

#pragma unroll 1
  for (int k0 = 0; k0 < K; k0 += BK) {
    const short8 a0 = cvt8(*(const float4*)(Ag0 + k0), *(const float4*)(Ag0 + k0 + 4));
    const short8 a1 = cvt8(*(const float4*)(Ag1 + k0), *(const float4*)(Ag1 + k0 + 4));
    const short8 b0 = cvt8(*(const float4*)(Bg0 + k0), *(const float4*)(Bg0 + k0 + 4));
    const short8 b1 = cvt8(*(const float4*)(Bg1 + k0), *(const float4*)(Bg1 + k0 + 4));
    __syncthreads();                 // prev iter's LDS reads done (WAR)
    *(short8*)&As[c0 * 8] = a0;
    *(short8*)&As[c1 * 8] = a1;
    *(short8*)&Bs[c0 * 8] = b0;
    *(short8*)&Bs[c1 * 8] = b1;
    __syncthreads();                 // tiles visible (RAW)

    short8 af[4], bfr[4];
#pragma unroll
    for (int i = 0; i < 4; ++i) {
      af[i]  = *(const short8*)&As[(wm * 64 + i * 16 + l16) * BK + quad * 8];
      bfr[i] = *(const short8*)&Bs[(wn * 64 + i * 16 + l16) * BK + quad * 8];
    }
#pragma unroll
    for (int mt = 0; mt < 4; ++mt)
#pragma unroll
      for (int nt = 0; nt < 4; ++nt)
        acc[mt][nt] = __builtin_amdgcn_mfma_f32_16x16x32_bf16(af[mt], bfr[nt], acc[mt][nt], 0, 0, 0);
  }

  if constexpr (EPI == EPI_MEANACC) {
    // fused mean-over-S: column sums -> atomicAdd into [B,D] fp32 accumulator
    float* eacc = (float*)outp;
    const int b = (int)(m0 >> 10);   // 1024 rows per batch; 128-row tiles never straddle
#pragma unroll
    for (int nt = 0; nt < 4; ++nt) {
      float cs = 0.f;
#pragma unroll
      for (int mt = 0; mt < 4; ++mt)
#pragma unroll
        for (int r = 0; r < 4; ++r) cs += acc[mt][nt][r];
      cs += __shfl_xor(cs, 16, 64);
      cs += __shfl_xor(cs, 32, 64);
      if (quad == 0) {
        const int col = (int)n0 + wn * 64 + nt * 16 + l16;
        atomicAdd(&eacc[b * Dd + col], cs);
      }
    }
  } else {
    float* out = (float*)outp;
#pragma unroll
    for (int nt = 0; nt < 4; ++nt) {
      const size_t col = n0 + wn * 64 + nt * 16 + l16;
      const float bv = bias[col];
#pragma unroll
      for (int mt = 0; mt < 4; ++mt) {
#pragma unroll
        for (int r = 0; r < 4; ++r) {
          const size_t row = m0 + wm * 64 + mt * 16 + quad * 4 + r;
          float v = acc[mt][nt][r] + bv;
          if constexpr (EPI == EPI_GELU)
            v = 0.5f * v * (1.f + erff(v * 0.70710678118654752f));
          out[row * N + col] = v;
        }
      }
    }
  }
}

// one wave per (b_local,h,q); 4 waves/block; qkv is a 4-batch chunk [4096,2304] fp32
__global__ __launch_bounds__(256) void attn_kernel(
    const float* __restrict__ qkv, const int* __restrict__ mask,
    float* __restrict__ ctx, const int b0)
{
  __shared__ __align__(16) float qs[4][HDd];
  __shared__ float ps[4][Ss];
  const int tid = threadIdx.x, wave = tid >> 6, lane = tid & 63;
  const int flat = blockIdx.x * 4 + wave;        // 4*4*1024 waves per chunk
  const int bl = flat >> 12, h = (flat >> 10) & 3, q = flat & 1023;
  const int b = b0 + bl;
  const size_t bbase = (size_t)bl * Ss * (3 * Dd);

  const float* Qp = qkv + bbase + (size_t)q * (3 * Dd) + h * HDd;
#pragma unroll
  for (int t = 0; t < 3; ++t) qs[wave][t * 64 + lane] = Qp[t * 64 + lane];
  __syncthreads();   // cheap hedge: all q-stage LDS writes visible

  const float scale = 0.07216878364870322f;  // 1/sqrt(192)
  float mx = -3.0e38f;
#pragma unroll 1
  for (int t = 0; t < 16; ++t) {
    const int j = t * 64 + lane;
    const float4* Kr = (const float4*)(qkv + bbase + (size_t)j * (3 * Dd) + Dd + h * HDd);
    float s = 0.f;
#pragma unroll 12
    for (int i = 0; i < 48; ++i) {
      const float4 kv = Kr[i];
      const float* qp = &qs[wave][i * 4];
      s += qp[0] * kv.x + qp[1] * kv.y + qp[2] * kv.z + qp[3] * kv.w;
    }
    s *= scale;
    if (mask[(b << 10) + j] == 0) s = -1.0e30f;   // key padding mask
    ps[wave][j] = s;
    mx = fmaxf(mx, s);
  }
#pragma unroll
  for (int off = 32; off > 0; off >>= 1) mx = fmaxf(mx, __shfl_xor(mx, off, 64));
  float sum = 0.f;
#pragma unroll 1
  for (int t = 0; t < 16; ++t) {
    const int j = t * 64 + lane;
    const float e = __expf(ps[wave][j] - mx);
    ps[wave][j] = e;
    sum += e;
  }
#pragma unroll
  for (int off = 32; off > 0; off >>= 1) sum += __shfl_xor(sum, off, 64);
  const float inv = 1.f / sum;

  const float* Vb = qkv + bbase + 2 * Dd + h * HDd + lane;
  float c0 = 0.f, c1 = 0.f, c2 = 0.f;
#pragma unroll 8
  for (int j = 0; j < Ss; ++j) {
    const float pj = ps[wave][j];
    const float* Vr = Vb + (size_t)j * (3 * Dd);
    c0 += pj * Vr[0];
    c1 += pj * Vr[64];
    c2 += pj * Vr[128];
  }
  float* Cp = ctx + ((size_t)b * Ss + q) * Dd + h * HDd + lane;
  Cp[0]   = c0 * inv;
  Cp[64]  = c1 * inv;
  Cp[128] = c2 * inv;
}

__global__ __launch_bounds__(256) void calc_idx(const int* __restrict__ mask, int* __restrict__ idx) {
  __shared__ int sm[256];
  const int b = blockIdx.x, tid = threadIdx.x;
  int s = 0;
  for (int i = tid; i < Ss; i += 256) s += mask[b * Ss + i];
  sm[tid] = s;
  __syncthreads();
  for (int o = 128; o > 0; o >>= 1) {
    if (tid < o) sm[tid] += sm[tid + o];
    __syncthreads();
  }
  if (tid == 0) idx[b] = sm[0] - 1;
}

// embedding = accum/1024 + mha_out_b; e1 = emb@asp_w^T+asp_b; e2 = emb@opi_w^T+opi_b (fp32)
// NOTE: eacc may alias e1 (accumulator lives in e1's output slot): all reads of eacc happen
// before the __syncthreads(), all writes after; block b touches only batch b's rows.
__global__ __launch_bounds__(256) void emb_e_kernel(
    const float* __restrict__ eacc, const float* __restrict__ outb,
    const float* __restrict__ aw, const float* __restrict__ ab,
    const float* __restrict__ ow, const float* __restrict__ ob,
    float* __restrict__ e1, float* __restrict__ e2)
{
  __shared__ float emb[Dd];
  const int b = blockIdx.x, tid = threadIdx.x;
  for (int i = tid; i < Dd; i += 256)
    emb[i] = eacc[b * Dd + i] * (1.f / 1024.f) + outb[i];
  __syncthreads();
  for (int n = tid; n < Dd; n += 256) {
    float s1 = ab[n], s2 = ob[n];
    const float* w1 = aw + (size_t)n * Dd;
    const float* w2 = ow + (size_t)n * Dd;
    for (int d = 0; d < Dd; ++d) {
      const float ev = emb[d];
      s1 += ev * w1[d];
      s2 += ev * w2[d];
    }
    e1[b * Dd + n] = s1;
    e2[b * Dd + n] = s2;
  }
}

__global__ __launch_bounds__(64) void imp_kernel(
    const float* __restrict__ e1, const float* __restrict__ e2,
    const float* __restrict__ wa, const float* __restrict__ ba,
    const float* __restrict__ wo, const float* __restrict__ bo,
    float* __restrict__ outa, float* __restrict__ outo)
{
  const int id = blockIdx.x, lane = threadIdx.x;
  const int b = id >> 2, which = (id >> 1) & 1, c = id & 1;
  const float* e = which ? e2 : e1;
  const float* w = which ? wo : wa;
  const float* bb = which ? bo : ba;
  float s = 0.f;
  for (int d = lane; d < Dd; d += 64) s += e[b * Dd + d] * w[c * Dd + d];
  for (int off = 32; off > 0; off >>= 1) s += __shfl_xor(s, off, 64);
  if (lane == 0) {
    float* o = which ? outo : outa;
    o[b * 2 + c] = s + bb[c];
  }
}

// se1: row0<-e1 then row idx<-e2 ; se2: row idx<-e2 then row0<-e1
__global__ __launch_bounds__(256) void scatter_kernel(
    const float* __restrict__ x, const float* __restrict__ e1,
    const float* __restrict__ e2, const int* __restrict__ idx,
    float* __restrict__ h1, float* __restrict__ h2)
{
  const int row = blockIdx.x;
  const int b = row >> 10, s = row & 1023;
  const int ix = idx[b];
  const size_t base = (size_t)row * Dd;
  for (int i = threadIdx.x; i < Dd; i += 256) {
    const float xv = x[base + i];
    const float v1 = e1[b * Dd + i];
    const float v2 = e2[b * Dd + i];
    h1[base + i] = (s == ix) ? v2 : ((s == 0) ? v1 : xv);
    h2[base + i] = (s == 0) ? v1 : ((s == ix) ? v2 : xv);
  }
}

// h = LayerNorm(pre + h)*g + b  (in place on h), one wave per row; pre/h pre-offset per chunk
__global__ __launch_bounds__(64) void ln_kernel(
    const float* __restrict__ pre, float* __restrict__ h,
    const float* __restrict__ g, const float* __restrict__ bb)
{
  const int row = blockIdx.x, lane = threadIdx.x;
  const size_t base = (size_t)row * Dd;
  float v[12];
  float s = 0.f, sq = 0.f;
#pragma unroll
  for (int t = 0; t < 12; ++t) {
    const int i = t * 64 + lane;
    const float val = pre[base + i] + h[base + i];
    v[t] = val;
    s += val;
    sq += val * val;
  }
#pragma unroll
  for (int off = 32; off > 0; off >>= 1) {
    s += __shfl_xor(s, off, 64);
    sq += __shfl_xor(sq, off, 64);
  }
  const float m = s * (1.f / 768.f);
  float var = sq * (1.f / 768.f) - m * m;
  var = fmaxf(var, 0.f);
  const float r = rsqrtf(var + 1e-12f);
#pragma unroll
  for (int t = 0; t < 12; ++t) {
    const int i = t * 64 + lane;
    h[base + i] = (v[t] - m) * r * g[i] + bb[i];
  }
}

// logits[row,0..2] = h[row,:]@w[c,:] + b[c]; blocks 0..16383 -> asp(h1), rest -> opi(h2)
__global__ __launch_bounds__(64) void logits_kernel(
    const float* __restrict__ h1, const float* __restrict__ h2,
    const float* __restrict__ wa, const float* __restrict__ ba,
    const float* __restrict__ wo, const float* __restrict__ bo,
    float* __restrict__ outa, float* __restrict__ outo)
{
  const int id = blockIdx.x, lane = threadIdx.x;
  const int which = id >> 14;
  const int row = id & 16383;
  const float* h = which ? h2 : h1;
  const float* w = which ? wo : wa;
  const float* bc = which ? bo : ba;
  const size_t base = (size_t)row * Dd;
  float s0 = 0.f, s1 = 0.f, s2 = 0.f;
#pragma unroll
  for (int t = 0; t < 12; ++t) {
    const int i = t * 64 + lane;
    const float hv = h[base + i];
    s0 += hv * w[i];
    s1 += hv * w[Dd + i];
    s2 += hv * w[2 * Dd + i];
  }
#pragma unroll
  for (int off = 32; off > 0; off >>= 1) {
    s0 += __shfl_xor(s0, off, 64);
    s1 += __shfl_xor(s1, off, 64);
    s2 += __shfl_xor(s2, off, 64);
  }
  if (lane == 0) {
    float* o = which ? outo : outa;
    o[(size_t)row * 3 + 0] = s0 + bc[0];
    o[(size_t)row * 3 + 1] = s1 + bc[1];
    o[(size_t)row * 3 + 2] = s2 + bc[2];
  }
}

__global__ __launch_bounds__(256) void copy16(const uint4* __restrict__ s, uint4* __restrict__ d, int n) {
  const int i = blockIdx.x * 256 + threadIdx.x;
  if (i < n) d[i] = s[i];
}

extern "C" void kernel_launch(void* const* d_in, const int* in_sizes, int n_in,
                              void* d_out, int out_size, void* d_ws, size_t ws_size,
                              hipStream_t stream)
{
  (void)in_sizes; (void)n_in; (void)out_size; (void)d_ws; (void)ws_size;  // d_ws UNUSED: size unknown, see R3 post-mortem
  const float* x        = (const float*)d_in[0];
  const int*   mask     = (const int*)d_in[1];
  const float* mha_in_w = (const float*)d_in[2];
  const float* mha_in_b = (const float*)d_in[3];
  const float* mha_out_w= (const float*)d_in[4];
  const float* mha_out_b= (const float*)d_in[5];
  const float* asp_w    = (const float*)d_in[6];
  const float* asp_b    = (const float*)d_in[7];
  const float* opi_w    = (const float*)d_in[8];
  const float* opi_b    = (const float*)d_in[9];
  const float* ia_w     = (const float*)d_in[10];
  const float* ia_b     = (const float*)d_in[11];
  const float* io_w     = (const float*)d_in[12];
  const float* io_b     = (const float*)d_in[13];
  const float* cls_a_w  = (const float*)d_in[26];
  const float* cls_a_b  = (const float*)d_in[27];
  const float* cls_o_w  = (const float*)d_in[28];
  const float* cls_o_b  = (const float*)d_in[29];

  // ---- output layout (fp32 elements, return order). ALL scratch lives in dead d_out regions. ----
  float* out   = (float*)d_out;
  float* o_la  = out;                        // logits_asp [16,1024,3]
  float* o_lo  = out + 49152;                // logits_opi; first 64B double as idx[16] until phase 9
  float* o_x   = out + 98304;                // x copy (written LAST); scratch: ctx -> interbuf+preC
  float* o_se1 = o_x + 12582912;             // se1; scratch: qkv chunk buffer until scatter
  float* o_se2 = o_se1 + 12582912;           // se2
  float* o_ia  = o_se2 + 12582912;           // imp_asp [16,2]
  float* o_io  = o_ia + 32;
  float* o_e1  = o_io + 32;                  // e1 [16,768]; doubles as mean accumulator before emb_e
  float* o_e2  = o_e1 + 12288;

  float* ctx      = o_x;                     // [16384,768] phases 2-3
  float* interbuf = o_x;                     // [2048,3072] FFN phases (ctx dead)
  float* preC     = o_x + 6291456;           // [2048,768] per-chunk pre-LN
  float* qkvbuf   = o_se1;                   // [4096,2304] (18.9MB*2) phases 2 only
  float* h1       = o_se1;
  float* h2       = o_se2;
  float* eacc     = o_e1;                    // [16,768] accumulator (aliases e1 slot; safe, see emb_e)
  int*   idxp     = (int*)o_lo;              // [16] until logits overwrites

  hipMemsetAsync(eacc, 0, Bb * Dd * sizeof(float), stream);
  calc_idx<<<Bb, 256, 0, stream>>>(mask, idxp);

  // QKV + attention, 4 chunks of 4 batches ([4096,2304] fp32 in o_se1)
  for (int c = 0; c < 4; ++c) {
    gemm_bt<EPI_F32><<<dim3(2304 / 128, 4096 / 128), 256, 0, stream>>>(
        x + (size_t)c * 4096 * Dd, mha_in_w, mha_in_b, qkvbuf, 2304, 768);
    attn_kernel<<<4096, 256, 0, stream>>>(qkvbuf, mask, ctx, c * 4);
  }

  // out-proj with fused mean-over-S -> eacc (full M)
  gemm_bt<EPI_MEANACC><<<dim3(768 / 128, 16384 / 128), 256, 0, stream>>>(
      ctx, mha_out_w, nullptr, eacc, 768, 768);

  emb_e_kernel<<<Bb, 256, 0, stream>>>(eacc, mha_out_b, asp_w, asp_b, opi_w, opi_b,
                                       o_e1, o_e2);
  imp_kernel<<<64, 64, 0, stream>>>(o_e1, o_e2, ia_w, ia_b, io_w, io_b, o_ia, o_io);
  scatter_kernel<<<16384, 256, 0, stream>>>(x, o_e1, o_e2, idxp, h1, h2);

  // decoder stacks in place on h1/h2; inter [2048,3072] + preC [2048,768] in o_x; LN per chunk
  for (int st = 0; st < 2; ++st) {
    float* h = st ? h2 : h1;
    const float* Wi = (const float*)d_in[14 + st * 6];
    const float* bi = (const float*)d_in[15 + st * 6];
    const float* Wo = (const float*)d_in[16 + st * 6];
    const float* bo = (const float*)d_in[17 + st * 6];
    const float* lg = (const float*)d_in[18 + st * 6];
    const float* lb = (const float*)d_in[19 + st * 6];
    for (int l = 0; l < 2; ++l) {
      for (int c = 0; c < 8; ++c) {
        float* hc = h + (size_t)c * 2048 * Dd;
        gemm_bt<EPI_GELU><<<dim3(3072 / 128, 2048 / 128), 256, 0, stream>>>(
            hc, Wi + (size_t)l * 3072 * 768, bi + l * 3072, interbuf, 3072, 768);
        gemm_bt<EPI_F32><<<dim3(768 / 128, 2048 / 128), 256, 0, stream>>>(
            interbuf, Wo + (size_t)l * 768 * 3072, bo + l * 768, preC, 768, 3072);
        ln_kernel<<<2048, 64, 0, stream>>>(preC, hc, lg + l * 768, lb + l * 768);
      }
    }
  }

  logits_kernel<<<32768, 64, 0, stream>>>(h1, h2, cls_a_w, cls_a_b, cls_o_w, cls_o_b,
                                          o_la, o_lo);
  // x copy LAST (o_x served as ctx/interbuf/preC scratch until here)
  copy16<<<12288, 256, 0, stream>>>((const uint4*)x, (uint4*)o_x, 3145728);
}